// Round 12
// baseline (272.985 us; speedup 1.0000x reference)
//
#include <hip/hip_runtime.h>
#include <hip/hip_bf16.h>

#define NN 64
#define BATCH 512
#define SP 60
#define SG 180
#define SEX 10
#define CATD 80
#define NA 5
#define NR 7
#define OO 8
#define II 8

typedef unsigned long long u64;
typedef unsigned short u16;
typedef unsigned int u32;
typedef unsigned char u8;

// ---- workspace layout (float offsets; rho/alpha only now) ----
#define OFF_RHOF  743344
#define OFF_RHOB  (OFF_RHOF + 1966080)
#define OFF_ALF   (OFF_RHOB + 1966080)
#define OFF_ALB   (OFF_ALF + 30720)

typedef _Float16 f16;
typedef _Float16 half2_t __attribute__((ext_vector_type(2)));
typedef _Float16 f16x8 __attribute__((ext_vector_type(8)));
typedef float f32x4 __attribute__((ext_vector_type(4)));

__device__ __forceinline__ float us2f(u16 v){
  return __uint_as_float(((u32)v) << 16);
}
__device__ __forceinline__ u16 f2bf(float f){
  __hip_bfloat16 h = __float2bfloat16(f);
  return *reinterpret_cast<u16*>(&h);
}
__device__ __forceinline__ float rcp_(float x){ return __builtin_amdgcn_rcpf(x); }
__device__ __forceinline__ float sigm(float x){
  return rcp_(1.f + __expf(-x));
}
__device__ __forceinline__ float tanh_(float x){
  float e = __expf(2.f*fabsf(x));
  float t = 1.f - 2.f*rcp_(e + 1.f);
  return copysignf(t, x);
}
__device__ __forceinline__ u32 pack2(float a, float b){
  half2_t h; h[0] = (f16)a; h[1] = (f16)b;
  return __builtin_bit_cast(u32, h);
}
__device__ __forceinline__ float fdot2_(u32 a, u32 b, float c){
  return __builtin_amdgcn_fdot2(__builtin_bit_cast(half2_t, a),
                                __builtin_bit_cast(half2_t, b), c, false);
}
__device__ __forceinline__ f16x8 bc16(uint4 v){ return __builtin_bit_cast(f16x8, v); }
__device__ __forceinline__ f32x4 mfma16(f16x8 a, f16x8 b, f32x4 c){
  return __builtin_amdgcn_mfma_f32_16x16x32_f16(a, b, c, 0, 0, 0);
}
// raw load with optional bf16 conversion (bit-identical to old conv_in path)
__device__ __forceinline__ float ldw(const void* p, size_t i, int isbf){
  return isbf ? us2f(((const u16*)p)[i]) : ((const float*)p)[i];
}

// r22: r21 + LDS cut for 3 blocks/CU. sZdc stored as f16 (-15.4KB ->
// 46.7KB total, 3x = 140KB <= 160KB) and __launch_bounds__(256,3).
// zdc is added pre-tanh; f16 storage adds <=5e-4 abs error (absmax
// headroom: 0.0039 passed earlier). Third co-resident block per CU
// gives a third independent instruction stream to fill the ~1200cy
// serial step spine that 2 streams left ~46% empty.
__global__ __launch_bounds__(256, 3) void dir_kernel(
  const int* __restrict__ adj, const void* zp_, const void* dzp_,
  const void* hasp_,
  const void* WihF_, const void* WhhF_, const void* bihF_, const void* bhhF_,
  const void* WihB_, const void* WhhB_, const void* bihB_, const void* bhhB_,
  const void* Wf_, const void* bf_, const void* Wb_, const void* bb_,
  float* __restrict__ ws)
{
  const int tid = threadIdx.x;
  const int w   = tid >> 6;         // wave id (0..3) == row tile mt
  const int u   = tid & 63;         // lane
  const int ml  = u & 15;           // MFMA col (consumer slot)
  const int q   = u >> 4;           // MFMA quad
  const int bid = blockIdx.x;
  const int bwd = bid >> 8;
  const int bp  = (bid & 255) << 1; // batch pair base {bp, bp+1}

  __shared__ int sIsBf;
  if (tid < 64){
    const u32* hw_ = (const u32*)hasp_;
    int f = 0;
    #pragma unroll
    for (int k=0;k<4;k++) f |= (hw_[tid*4 + k] == 0x3F803F80u) ? 1 : 0;
    u64 m = __ballot(f != 0);
    if (tid == 0) sIsBf = (m != 0ULL) ? 1 : 0;
  }
  __syncthreads();
  const int isbf = sIsBf;

  const void* Wihp  = bwd ? WihB_ : WihF_;
  const void* Whhp  = bwd ? WhhB_ : WhhF_;
  const void* bihp  = bwd ? bihB_ : bihF_;
  const void* bhhp  = bwd ? bhhB_ : bhhF_;
  const void* Wcatp = bwd ? Wb_   : Wf_;
  const void* bcatp = bwd ? bb_   : bf_;
  float* rho   = ws + (bwd ? OFF_RHOB : OFF_RHOF);  // [64][512][60]
  float* alpha = ws + (bwd ? OFF_ALB  : OFF_ALF);   // [512][60]

  __shared__ uint4 sH4[2][65][9];     // h rows per elem; half63=1.0 (bias ch)
  __shared__ uint4 sRhoPad[2][8];     // rho_t halves; half63=1.0
  __shared__ uint4 sRhoHist[2][8][8]; // tail rho history; half63=1.0
  __shared__ u16 sZdc[2][NN][SP];     // bias + z/dz contribution (f16 bits)
  __shared__ u32 sZp[2][NN][5];
  __shared__ u32 sDZp[2][NN][5];
  __shared__ float sHas[2][NN];
  __shared__ u64 sRowM[NN];
  __shared__ u8 sConsL[NN][64];       // consumer lists (batch-independent)
  __shared__ int sConsCnt[NN];

  #define ROWB(E,I) ((char*)&sH4[(E)][(I)][0])
  const u32 BIASW = 0x3C000000u;      // halves {0, 1.0h}

  // ---- staging (raw reads + conversion) ----
  {
    if (tid < 64){
      u64 rowm = 0;
      for (int j=0;j<64;j++) rowm |= ((u64)(adj[tid*64+j]!=0))<<j;
      sRowM[tid] = rowm;
    }
    if (tid < 128){
      const int e = tid >> 6, n = tid & 63;
      sHas[e][n] = ldw(hasp_, (size_t)(bp+e)*NN + n, isbf);
    }
    for (int idx=tid; idx<2*65*9; idx+=256){
      uint4 v = {0,0,0,0};
      if ((idx % 9) == 7) v.w = BIASW;       // half63 = 1.0
      ((uint4*)sH4)[idx] = v;
    }
    if (tid < 16){ uint4 v={0,0,0,0}; if ((tid&7)==7) v.w = BIASW; ((uint4*)sRhoPad)[tid]=v; }
    if (tid < 128){ uint4 v={0,0,0,0}; if ((tid&7)==7) v.w = BIASW; ((uint4*)sRhoHist)[tid]=v; }
    for (int idx=tid; idx<2*NN*5; idx+=256){
      int e = idx/(NN*5), rem = idx%(NN*5), n2=rem/5, p2=rem%5;
      const size_t base = (size_t)(bp+e)*NN*SEX + n2*SEX + 2*p2;
      sZp [e][n2][p2] = pack2(ldw(zp_,  base, isbf), ldw(zp_,  base+1, isbf));
      sDZp[e][n2][p2] = pack2(ldw(dzp_, base, isbf), ldw(dzp_, base+1, isbf));
    }
  }
  __syncthreads();
  if (tid < 64){
    u64 cm = 0;
    if (bwd) for (int i2=0;i2<64;i2++) cm |= ((sRowM[i2]>>tid)&1ULL)<<i2;
    u64 m = bwd ? cm : sRowM[tid];          // consumers of node tid
    int c = 0;
    while (m){ int i2 = (int)__builtin_ctzll(m); m &= m-1; sConsL[tid][c++] = (u8)i2; }
    sConsCnt[tid] = c;
  }
  // zdc precompute: sZdc[e][t][uu] = bcat[uu] + Wz.z + Wdz.dz (bias folded).
  {
    const int uu = tid & 63;
    const int tw = tid >> 6;
    if (uu < SP){
      u32 wz[10];
      #pragma unroll
      for (int p=0;p<10;p++)
        wz[p] = pack2(ldw(Wcatp, uu*CATD + 60 + 2*p,     isbf),
                      ldw(Wcatp, uu*CATD + 60 + 2*p + 1, isbf));
      const float bb0 = ldw(bcatp, uu, isbf);
      for (int et=tw; et<2*NN; et+=4){
        const int e = et >> 6, t2 = et & 63;
        float c = bb0;
        #pragma unroll
        for (int p=0;p<5;p++){
          c = fdot2_(wz[p],   sZp [e][t2][p], c);
          c = fdot2_(wz[5+p], sDZp[e][t2][p], c);
        }
        sZdc[e][t2][uu] = __builtin_bit_cast(u16, (f16)c);
      }
    }
  }

  // ---- A fragments (wave w owns mt = w), shared across both elems ----
  f16x8 Ar[4], Az[4], Anh[2], Ani[2], Ac[2];
  {
    const int R = 16*w + ml;
    const bool rok = (R < SP);
    #pragma unroll
    for (int kt=0; kt<4; kt++){
      f16x8 vr, vz;
      #pragma unroll
      for (int j=0;j<8;j++){
        const int K = 32*kt + 8*q + j;
        float wr=0.f, wz2=0.f;
        if (rok){
          if (K < SP){ wr = ldw(Whhp, R*SP+K, isbf); wz2 = ldw(Whhp, (60+R)*SP+K, isbf); }
          else if (K >= 64 && K < 64+SP){ wr = ldw(Wihp, R*SP+(K-64), isbf); wz2 = ldw(Wihp, (60+R)*SP+(K-64), isbf); }
          else if (K == 127){ wr = ldw(bhhp,R,isbf)+ldw(bihp,R,isbf); wz2 = ldw(bhhp,60+R,isbf)+ldw(bihp,60+R,isbf); }
        }
        vr[j]=(f16)wr; vz[j]=(f16)wz2;
      }
      Ar[kt]=vr; Az[kt]=vz;
    }
    #pragma unroll
    for (int kt=0; kt<2; kt++){
      f16x8 vn, vi, vc;
      #pragma unroll
      for (int j=0;j<8;j++){
        const int K = 32*kt + 8*q + j;
        float wn=0.f, wi=0.f, wcv=0.f;
        if (rok){
          if (K < SP){ wn = ldw(Whhp,(120+R)*SP+K,isbf); wi = ldw(Wihp,(120+R)*SP+K,isbf); wcv = ldw(Wcatp,R*CATD+K,isbf); }
          else if (K == 63){ wn = ldw(bhhp,120+R,isbf); wi = ldw(bihp,120+R,isbf); }
        }
        vn[j]=(f16)wn; vi[j]=(f16)wi; vc[j]=(f16)wcv;
      }
      Anh[kt]=vn; Ani[kt]=vi; Ac[kt]=vc;
    }
  }
  __syncthreads();   // lists + zdc + LDS init visible

  // gates: GRU gate math + h read-modify-write, window [32w,32w+32) of rowb.
  auto gates = [&](f32x4 Dr, f32x4 Dz, f32x4 Dn, f32x4 Gn,
                   char* rowb, bool wr, float bl){
    char* rp = rowb + 32*w + 8*q;
    uint2 h2 = *(uint2*)rp;
    half2_t ha = __builtin_bit_cast(half2_t, h2.x);
    half2_t hb = __builtin_bit_cast(half2_t, h2.y);
    float hold[4] = { (float)ha[0], (float)ha[1], (float)hb[0], (float)hb[1] };
    float hw[4];
    #pragma unroll
    for (int reg=0;reg<4;reg++){
      float r_ = sigm(Dr[reg]);
      float zg = sigm(Dz[reg]);
      float nv = tanh_(Gn[reg] + r_*Dn[reg]);
      float hn_ = (1.f - zg)*nv + zg*hold[reg];
      hw[reg] = (bl != 0.f) ? hn_ : hold[reg];   // bl is exactly 0 or 1
    }
    if (wr && !(w==3 && q==3)){
      uint2 o; o.x = pack2(hw[0],hw[1]); o.y = pack2(hw[2],hw[3]);
      *(uint2*)rp = o;
    }
  };

  // full 11-MFMA pass (latent p>=2 groups + tail)
  auto fullpass = [&](f16x8 Bh0, f16x8 Bh1, f16x8 Br0, f16x8 Br1,
                      f32x4 Gn, char* rowb, bool wr, float bl){
    f32x4 Dr={0,0,0,0}, Dz={0,0,0,0}, Dn={0,0,0,0};
    Dr = mfma16(Ar[0], Bh0, Dr); Dr = mfma16(Ar[1], Bh1, Dr);
    Dr = mfma16(Ar[2], Br0, Dr); Dr = mfma16(Ar[3], Br1, Dr);
    Dz = mfma16(Az[0], Bh0, Dz); Dz = mfma16(Az[1], Bh1, Dz);
    Dz = mfma16(Az[2], Br0, Dz); Dz = mfma16(Az[3], Br1, Dz);
    Dn = mfma16(Anh[0], Bh0, Dn); Dn = mfma16(Anh[1], Bh1, Dn);
    gates(Dr, Dz, Dn, Gn, rowb, wr, bl);
  };

  // ---- 64 pipelined steps, 2 barriers each, 2 batch elems ----
  int t = bwd ? 63 : 0;
  const int dt = bwd ? -1 : 1;
  for (int s=0; s<64; s++, t+=dt){
    const int cnt = sConsCnt[t];
    const float bl0 = sHas[0][t];
    const float bl1 = sHas[1][t];
    const bool a0 = (bl0 != 0.f), a1 = (bl1 != 0.f);
    const int nact = (int)a0 + (int)a1;
    const bool act   = (cnt > 0) && (nact > 0);
    const bool fastp = act && (nact == 2) && (cnt <= 8);   // mixed single pass
    const bool snglp = act && (nact == 1);                 // one elem active
    const bool dualp = act && (nact == 2) && (cnt > 8);
    const bool g1d   = dualp && (cnt > 16);
    const bool g1s   = snglp && (cnt > 16);
    const int  ea    = a0 ? 0 : 1;
    const float bla  = a0 ? bl0 : bl1;

    // pre-R: consumer-row Bh preloads (reads only)
    int ci0 = 64, ci1 = 64, cim = 64;
    const int eh = ml >> 3;                     // fast-path elem per column
    f16x8 Bm0={}, Bm1={};
    f16x8 B0a={}, B1a={}, C0a={}, C1a={};       // snglp groups (elem ea)
    f16x8 Bh0e0={}, Bh1e0={}, Bh0e1={}, Bh1e1={};
    f16x8 Ch0e0={}, Ch1e0={}, Ch0e1={}, Ch1e1={};
    if (fastp){
      const int sl = ml & 7;
      cim = (sl < cnt) ? (int)sConsL[t][sl] : 64;
      Bm0 = bc16(sH4[eh][cim][q]);
      Bm1 = bc16(sH4[eh][cim][4+q]);
    } else if (snglp){
      ci0 = (ml < cnt) ? (int)sConsL[t][ml] : 64;
      B0a = bc16(sH4[ea][ci0][q]); B1a = bc16(sH4[ea][ci0][4+q]);
      if (g1s){
        ci1 = (16 + ml < cnt) ? (int)sConsL[t][16 + ml] : 64;
        C0a = bc16(sH4[ea][ci1][q]); C1a = bc16(sH4[ea][ci1][4+q]);
      }
    } else if (dualp){
      ci0 = (ml < cnt) ? (int)sConsL[t][ml] : 64;
      Bh0e0 = bc16(sH4[0][ci0][q]); Bh1e0 = bc16(sH4[0][ci0][4+q]);
      Bh0e1 = bc16(sH4[1][ci0][q]); Bh1e1 = bc16(sH4[1][ci0][4+q]);
      if (g1d){
        ci1 = (16 + ml < cnt) ? (int)sConsL[t][16 + ml] : 64;
        Ch0e0 = bc16(sH4[0][ci1][q]); Ch1e0 = bc16(sH4[0][ci1][4+q]);
        Ch0e1 = bc16(sH4[1][ci1][q]); Ch1e1 = bc16(sH4[1][ci1][4+q]);
      }
    }

    // phase 1 matvec, packed: cols 0-3 elem0, 4-7 elem1 (e = (ml>>2)&1).
    {
      const int em = (ml >> 2) & 1;
      const f16x8 Hm0 = bc16(sH4[em][t][q]);
      const f16x8 Hm1 = bc16(sH4[em][t][4+q]);
      f32x4 Rv = {0,0,0,0};
      Rv = mfma16(Ac[0], Hm0, Rv);
      Rv = mfma16(Ac[1], Hm1, Rv);
      const int row = 16*w + 4*q + (ml & 3);
      if (ml < 8 && row < SP){
        const int m3 = ml & 3;
        float vv = Rv[0];
        vv = (m3==1) ? Rv[1] : vv;
        vv = (m3==2) ? Rv[2] : vv;
        vv = (m3==3) ? Rv[3] : vv;
        vv += (float)__builtin_bit_cast(f16, sZdc[em][t][row]);
        if (!bwd) vv = tanh_(vv);
        *(f16*)((char*)&sRhoPad[em][0] + 2*row) = (f16)vv;
        const int slot = bwd ? t : (t - (NN-OO));
        if (slot >= 0 && slot < 8)
          *(f16*)((char*)&sRhoHist[em][slot][0] + 2*row) = (f16)vv;
        rho[((size_t)t*BATCH + bp + em)*SP + row] = vv;   // fire & forget
      }
    }
    __syncthreads();   // R: rho visible; pre-R h reads done before writes

    if (fastp){
      // mixed single pass: per-lane elem eh, consumer cim
      const f16x8 Brm0 = bc16(sRhoPad[eh][q]);
      const f16x8 Brm1 = bc16(sRhoPad[eh][4+q]);
      f32x4 Gn={0,0,0,0};
      Gn = mfma16(Ani[0], Brm0, Gn); Gn = mfma16(Ani[1], Brm1, Gn);
      f32x4 Dr={0,0,0,0}, Dz={0,0,0,0}, Dn={0,0,0,0};
      Dr = mfma16(Ar[2], Brm0, Dr); Dr = mfma16(Ar[3], Brm1, Dr);
      Dr = mfma16(Ar[0], Bm0,  Dr); Dr = mfma16(Ar[1], Bm1,  Dr);
      Dz = mfma16(Az[2], Brm0, Dz); Dz = mfma16(Az[3], Brm1, Dz);
      Dz = mfma16(Az[0], Bm0,  Dz); Dz = mfma16(Az[1], Bm1,  Dz);
      Dn = mfma16(Anh[0], Bm0, Dn); Dn = mfma16(Anh[1], Bm1, Dn);
      gates(Dr, Dz, Dn, Gn, ROWB(eh, cim), (ml & 7) < cnt, eh ? bl1 : bl0);
    } else if (snglp){
      // one elem active: single-elem passes (half the dual work)
      const f16x8 Br0 = bc16(sRhoPad[ea][q]);
      const f16x8 Br1 = bc16(sRhoPad[ea][4+q]);
      f32x4 Gn={0,0,0,0};
      Gn = mfma16(Ani[0], Br0, Gn); Gn = mfma16(Ani[1], Br1, Gn);
      f32x4 Pr={0,0,0,0};
      Pr = mfma16(Ar[2], Br0, Pr); Pr = mfma16(Ar[3], Br1, Pr);
      f32x4 Pz={0,0,0,0};
      Pz = mfma16(Az[2], Br0, Pz); Pz = mfma16(Az[3], Br1, Pz);
      {
        f32x4 Dr=Pr, Dz=Pz, Dn={0,0,0,0};
        Dr = mfma16(Ar[0], B0a, Dr);  Dr = mfma16(Ar[1], B1a, Dr);
        Dz = mfma16(Az[0], B0a, Dz);  Dz = mfma16(Az[1], B1a, Dz);
        Dn = mfma16(Anh[0], B0a, Dn); Dn = mfma16(Anh[1], B1a, Dn);
        gates(Dr, Dz, Dn, Gn, ROWB(ea,ci0), ml < cnt, bla);
      }
      if (g1s){
        f32x4 Dr=Pr, Dz=Pz, Dn={0,0,0,0};
        Dr = mfma16(Ar[0], C0a, Dr);  Dr = mfma16(Ar[1], C1a, Dr);
        Dz = mfma16(Az[0], C0a, Dz);  Dz = mfma16(Az[1], C1a, Dz);
        Dn = mfma16(Anh[0], C0a, Dn); Dn = mfma16(Anh[1], C1a, Dn);
        gates(Dr, Dz, Dn, Gn, ROWB(ea,ci1), 16 + ml < cnt, bla);
      }
      for (int p=2; 16*p < cnt; p++){       // latent (cnt<=32 for this input)
        const int idxp = 16*p + ml;
        const int ci = (idxp < cnt) ? (int)sConsL[t][idxp] : 64;
        fullpass(bc16(sH4[ea][ci][q]), bc16(sH4[ea][ci][4+q]),
                 Br0, Br1, Gn, ROWB(ea,ci), idxp < cnt, bla);
      }
    } else if (dualp){
      const f16x8 Br0e0 = bc16(sRhoPad[0][q]);
      const f16x8 Br1e0 = bc16(sRhoPad[0][4+q]);
      const f16x8 Br0e1 = bc16(sRhoPad[1][q]);
      const f16x8 Br1e1 = bc16(sRhoPad[1][4+q]);
      f32x4 Gn0={0,0,0,0}, Gn1={0,0,0,0};
      Gn0 = mfma16(Ani[0], Br0e0, Gn0);  Gn1 = mfma16(Ani[0], Br0e1, Gn1);
      Gn0 = mfma16(Ani[1], Br1e0, Gn0);  Gn1 = mfma16(Ani[1], Br1e1, Gn1);
      f32x4 Pr0={0,0,0,0}, Pr1={0,0,0,0};
      Pr0 = mfma16(Ar[2], Br0e0, Pr0);   Pr1 = mfma16(Ar[2], Br0e1, Pr1);
      Pr0 = mfma16(Ar[3], Br1e0, Pr0);   Pr1 = mfma16(Ar[3], Br1e1, Pr1);
      f32x4 Pz0={0,0,0,0}, Pz1={0,0,0,0};
      Pz0 = mfma16(Az[2], Br0e0, Pz0);   Pz1 = mfma16(Az[2], Br0e1, Pz1);
      Pz0 = mfma16(Az[3], Br1e0, Pz0);   Pz1 = mfma16(Az[3], Br1e1, Pz1);

      { // group 0, both elems interleaved
        f32x4 Dr0=Pr0, Dz0=Pz0, Dn0={0,0,0,0};
        f32x4 Dr1=Pr1, Dz1=Pz1, Dn1={0,0,0,0};
        Dr0 = mfma16(Ar[0], Bh0e0, Dr0);  Dr1 = mfma16(Ar[0], Bh0e1, Dr1);
        Dr0 = mfma16(Ar[1], Bh1e0, Dr0);  Dr1 = mfma16(Ar[1], Bh1e1, Dr1);
        Dz0 = mfma16(Az[0], Bh0e0, Dz0);  Dz1 = mfma16(Az[0], Bh0e1, Dz1);
        Dz0 = mfma16(Az[1], Bh1e0, Dz0);  Dz1 = mfma16(Az[1], Bh1e1, Dz1);
        Dn0 = mfma16(Anh[0], Bh0e0, Dn0); Dn1 = mfma16(Anh[0], Bh0e1, Dn1);
        Dn0 = mfma16(Anh[1], Bh1e0, Dn0); Dn1 = mfma16(Anh[1], Bh1e1, Dn1);
        gates(Dr0, Dz0, Dn0, Gn0, ROWB(0,ci0), ml < cnt, bl0);
        gates(Dr1, Dz1, Dn1, Gn1, ROWB(1,ci0), ml < cnt, bl1);
      }
      if (g1d){
        f32x4 Dr0=Pr0, Dz0=Pz0, Dn0={0,0,0,0};
        f32x4 Dr1=Pr1, Dz1=Pz1, Dn1={0,0,0,0};
        Dr0 = mfma16(Ar[0], Ch0e0, Dr0);  Dr1 = mfma16(Ar[0], Ch0e1, Dr1);
        Dr0 = mfma16(Ar[1], Ch1e0, Dr0);  Dr1 = mfma16(Ar[1], Ch1e1, Dr1);
        Dz0 = mfma16(Az[0], Ch0e0, Dz0);  Dz1 = mfma16(Az[0], Ch0e1, Dz1);
        Dz0 = mfma16(Az[1], Ch1e0, Dz0);  Dz1 = mfma16(Az[1], Ch1e1, Dz1);
        Dn0 = mfma16(Anh[0], Ch0e0, Dn0); Dn1 = mfma16(Anh[0], Ch0e1, Dn1);
        Dn0 = mfma16(Anh[1], Ch1e0, Dn0); Dn1 = mfma16(Anh[1], Ch1e1, Dn1);
        gates(Dr0, Dz0, Dn0, Gn0, ROWB(0,ci1), 16 + ml < cnt, bl0);
        gates(Dr1, Dz1, Dn1, Gn1, ROWB(1,ci1), 16 + ml < cnt, bl1);
      }
      for (int p=2; 16*p < cnt; p++){       // latent
        const int idxp = 16*p + ml;
        const int ci = (idxp < cnt) ? (int)sConsL[t][idxp] : 64;
        fullpass(bc16(sH4[0][ci][q]), bc16(sH4[0][ci][4+q]),
                 Br0e0, Br1e0, Gn0, ROWB(0,ci), idxp < cnt, bl0);
        fullpass(bc16(sH4[1][ci][q]), bc16(sH4[1][ci][4+q]),
                 Br0e1, Br1e1, Gn1, ROWB(1,ci), idxp < cnt, bl1);
      }
    }
    __syncthreads();   // C: h writes visible to next step's reads
  }

  // ---- alpha tail: 8 GRU steps, mixed-column packed (cols 0-7 elem0,
  // 8-15 elem1; per-lane e=ml>>3; writes at ml==0 / ml==8) ----
  for (int s2=0; s2<8; s2++){
    const int i = bwd ? (7 - s2) : (NN - OO + s2);
    const int slot = bwd ? i : (i - (NN-OO));
    const int et = ml >> 3;
    const f16x8 Th0 = bc16(sH4[et][64][q]);
    const f16x8 Th1 = bc16(sH4[et][64][4+q]);
    const f16x8 Tr0 = bc16(sRhoHist[et][slot][q]);
    const f16x8 Tr1 = bc16(sRhoHist[et][slot][4+q]);
    f32x4 Gt={0,0,0,0};
    Gt = mfma16(Ani[0], Tr0, Gt);
    Gt = mfma16(Ani[1], Tr1, Gt);
    __syncthreads();   // all waves' row-64 reads done before writes
    fullpass(Th0, Th1, Tr0, Tr1, Gt, ROWB(et,64), (ml&7)==0,
             et ? sHas[1][i] : sHas[0][i]);
    __syncthreads();   // writes visible to next tail step
  }
  if (tid < SP){
    alpha[(size_t)(bp  )*SP + tid] = (float)*(const f16*)(ROWB(0,64) + 2*tid);
    alpha[(size_t)(bp+1)*SP + tid] = (float)*(const f16*)(ROWB(1,64) + 2*tid);
  }
  #undef ROWB
}

// One block per batch element: psi + softmaxes, omega, value -> d_out.
// r21: own bf16 detect; weights read raw with conversion (conv_in gone).
__global__ __launch_bounds__(256, 1) void head_kernel(
  const void* hasp_, const void* Wa_, const void* ba_, const void* Wc_,
  const void* bc_, const void* Wu_, const void* bu_,
  float* __restrict__ ws, void* __restrict__ outp)
{
  const int b = blockIdx.x;
  const int tid = threadIdx.x;

  __shared__ int sIsBf;
  if (tid < 64){
    const u32* hw_ = (const u32*)hasp_;
    int f = 0;
    #pragma unroll
    for (int k=0;k<4;k++) f |= (hw_[tid*4 + k] == 0x3F803F80u) ? 1 : 0;
    u64 m = __ballot(f != 0);
    if (tid == 0) sIsBf = (m != 0ULL) ? 1 : 0;
  }
  __syncthreads();
  const int isbf = sIsBf;

  const float* rhoF   = ws + OFF_RHOF;
  const float* rhoB   = ws + OFF_RHOB;
  const float* alphaF = ws + OFF_ALF;
  const float* alphaB = ws + OFF_ALB;

  __shared__ float sF[NN][122];    // 488B stride: float2-aligned
  __shared__ float sAB[120];
  __shared__ float sWu[NR*120];
  __shared__ float sHasR[NN];
  __shared__ float sPsi[NR][NN];
  __shared__ float sOm[NA];

  auto wout = [&](int idx, float v){
    if (isbf) ((u16*)outp)[idx] = f2bf(v);
    else      ((float*)outp)[idx] = v;
  };

  for (int idx=tid; idx<NN*SP; idx+=256){
    int n = idx/SP, s = idx%SP;
    sF[n][s]    = rhoF[((size_t)n*BATCH + b)*SP + s];
    sF[n][60+s] = rhoB[((size_t)n*BATCH + b)*SP + s];
  }
  for (int idx=tid; idx<120; idx+=256)
    sAB[idx] = (idx<60) ? alphaF[(size_t)b*SP + idx] : alphaB[(size_t)b*SP + idx-60];
  for (int idx=tid; idx<NR*120; idx+=256) sWu[idx] = ldw(Wu_, idx, isbf);
  for (int idx=tid; idx<NN; idx+=256) sHasR[idx] = ldw(hasp_, (size_t)b*NN + idx, isbf);
  __syncthreads();

  for (int idx=tid; idx<NR*NN; idx+=256){
    int r = idx/NN, n = idx%NN;
    const float2* fn = (const float2*)&sF[n][0];
    const float2* wr = (const float2*)&sWu[r*120];
    float acc = ldw(bu_, r, isbf);
    #pragma unroll 6
    for (int s2=0;s2<60;s2++){
      float2 a = fn[s2], c = wr[s2];
      acc += a.x*c.x;
      acc += a.y*c.y;
    }
    sPsi[r][n] = (sHasR[n] != 0.f) ? acc : -60.f;
  }
  if (tid >= 64 && tid < 64+NA){
    int a = tid - 64;
    float acc = ldw(ba_, a, isbf);
    for (int s=0;s<120;s++) acc += sAB[s]*ldw(Wa_, a*120+s, isbf);
    sOm[a] = acc;
  }
  if (tid == 70){
    float acc = ldw(bc_, 0, isbf);
    for (int s=0;s<120;s++) acc += sAB[s]*ldw(Wc_, s, isbf);
    wout(2560 + BATCH*NR*NN + b, acc);                 // value
  }
  __syncthreads();

  if (tid < NR*32){
    const int r = tid >> 5, l = tid & 31;
    float v0 = sPsi[r][l], v1 = sPsi[r][l+32];
    float m = fmaxf(v0, v1);
    #pragma unroll
    for (int o=16;o>0;o>>=1) m = fmaxf(m, __shfl_xor(m, o, 64));
    float e0 = __expf(v0 - m), e1 = __expf(v1 - m);
    float ssum = e0 + e1;
    #pragma unroll
    for (int o=16;o>0;o>>=1) ssum += __shfl_xor(ssum, o, 64);
    float rinv = 1.f/ssum;
    wout(2560 + (size_t)b*NR*NN + r*NN + l,    e0*rinv);   // role_prob
    wout(2560 + (size_t)b*NR*NN + r*NN + l+32, e1*rinv);
  }
  if (tid == 224){   // idle lane in the softmax phase
    float m = -1e30f;
    for (int a=0;a<NA;a++) m = fmaxf(m, sOm[a]);
    float e[NA]; float ssum = 0.f;
    for (int a=0;a<NA;a++){ e[a] = __expf(sOm[a]-m); ssum += e[a]; }
    for (int a=0;a<NA;a++) wout(b*NA + a, e[a]/ssum);  // instr_prob
  }
}

extern "C" void kernel_launch(void* const* d_in, const int* in_sizes, int n_in,
                              void* d_out, int out_size, void* d_ws, size_t ws_size,
                              hipStream_t stream)
{
  const int* adj = (const int*)d_in[3];
  float* ws = (float*)d_ws;

  dir_kernel<<<512, 256, 0, stream>>>(
      adj, d_in[0], d_in[1], d_in[2],
      d_in[4], d_in[5], d_in[6], d_in[7],
      d_in[8], d_in[9], d_in[10], d_in[11],
      d_in[12], d_in[13], d_in[14], d_in[15], ws);

  head_kernel<<<512, 256, 0, stream>>>(
      d_in[2], d_in[16], d_in[17], d_in[18], d_in[19],
      d_in[20], d_in[21], ws, d_out);
}

// Round 13
// 250.406 us; speedup vs baseline: 1.0902x; 1.0902x over previous
//
#include <hip/hip_runtime.h>
#include <hip/hip_bf16.h>

#define NN 64
#define BATCH 512
#define SP 60
#define SG 180
#define SEX 10
#define CATD 80
#define NA 5
#define NR 7
#define OO 8
#define II 8

typedef unsigned long long u64;
typedef unsigned short u16;
typedef unsigned int u32;
typedef unsigned char u8;

// ---- workspace layout (float offsets; rho/alpha only now) ----
#define OFF_RHOF  743344
#define OFF_RHOB  (OFF_RHOF + 1966080)
#define OFF_ALF   (OFF_RHOB + 1966080)
#define OFF_ALB   (OFF_ALF + 30720)

typedef _Float16 f16;
typedef _Float16 half2_t __attribute__((ext_vector_type(2)));
typedef _Float16 f16x8 __attribute__((ext_vector_type(8)));
typedef float f32x4 __attribute__((ext_vector_type(4)));

__device__ __forceinline__ float us2f(u16 v){
  return __uint_as_float(((u32)v) << 16);
}
__device__ __forceinline__ u16 f2bf(float f){
  __hip_bfloat16 h = __float2bfloat16(f);
  return *reinterpret_cast<u16*>(&h);
}
__device__ __forceinline__ float rcp_(float x){ return __builtin_amdgcn_rcpf(x); }
__device__ __forceinline__ float sigm(float x){
  return rcp_(1.f + __expf(-x));
}
__device__ __forceinline__ float tanh_(float x){
  float e = __expf(2.f*fabsf(x));
  float t = 1.f - 2.f*rcp_(e + 1.f);
  return copysignf(t, x);
}
__device__ __forceinline__ u32 pack2(float a, float b){
  half2_t h; h[0] = (f16)a; h[1] = (f16)b;
  return __builtin_bit_cast(u32, h);
}
__device__ __forceinline__ float fdot2_(u32 a, u32 b, float c){
  return __builtin_amdgcn_fdot2(__builtin_bit_cast(half2_t, a),
                                __builtin_bit_cast(half2_t, b), c, false);
}
__device__ __forceinline__ f16x8 bc16(uint4 v){ return __builtin_bit_cast(f16x8, v); }
__device__ __forceinline__ f32x4 mfma16(f16x8 a, f16x8 b, f32x4 c){
  return __builtin_amdgcn_mfma_f32_16x16x32_f16(a, b, c, 0, 0, 0);
}
// raw load with optional bf16 conversion (bit-identical to old conv_in path)
__device__ __forceinline__ float ldw(const void* p, size_t i, int isbf){
  return isbf ? us2f(((const u16*)p)[i]) : ((const float*)p)[i];
}

// r23: r22's LDS cut (f16 sZdc -> 47.1KB, 3 blocks/CU by LDS) but WITHOUT
// the register cap that sank r22: __launch_bounds__(256,2) keeps the
// allocator at r21's 104 VGPR (no spill; r22's (256,3) forced 84 VGPR ->
// +25MB scratch traffic). HW occupancy = min(LDS 3, VGPR floor(512/104)=4)
// = 3 blocks/CU -- the third stream without strangling registers.
__global__ __launch_bounds__(256, 2) void dir_kernel(
  const int* __restrict__ adj, const void* zp_, const void* dzp_,
  const void* hasp_,
  const void* WihF_, const void* WhhF_, const void* bihF_, const void* bhhF_,
  const void* WihB_, const void* WhhB_, const void* bihB_, const void* bhhB_,
  const void* Wf_, const void* bf_, const void* Wb_, const void* bb_,
  float* __restrict__ ws)
{
  const int tid = threadIdx.x;
  const int w   = tid >> 6;         // wave id (0..3) == row tile mt
  const int u   = tid & 63;         // lane
  const int ml  = u & 15;           // MFMA col (consumer slot)
  const int q   = u >> 4;           // MFMA quad
  const int bid = blockIdx.x;
  const int bwd = bid >> 8;
  const int bp  = (bid & 255) << 1; // batch pair base {bp, bp+1}

  __shared__ int sIsBf;
  if (tid < 64){
    const u32* hw_ = (const u32*)hasp_;
    int f = 0;
    #pragma unroll
    for (int k=0;k<4;k++) f |= (hw_[tid*4 + k] == 0x3F803F80u) ? 1 : 0;
    u64 m = __ballot(f != 0);
    if (tid == 0) sIsBf = (m != 0ULL) ? 1 : 0;
  }
  __syncthreads();
  const int isbf = sIsBf;

  const void* Wihp  = bwd ? WihB_ : WihF_;
  const void* Whhp  = bwd ? WhhB_ : WhhF_;
  const void* bihp  = bwd ? bihB_ : bihF_;
  const void* bhhp  = bwd ? bhhB_ : bhhF_;
  const void* Wcatp = bwd ? Wb_   : Wf_;
  const void* bcatp = bwd ? bb_   : bf_;
  float* rho   = ws + (bwd ? OFF_RHOB : OFF_RHOF);  // [64][512][60]
  float* alpha = ws + (bwd ? OFF_ALB  : OFF_ALF);   // [512][60]

  __shared__ uint4 sH4[2][65][9];     // h rows per elem; half63=1.0 (bias ch)
  __shared__ uint4 sRhoPad[2][8];     // rho_t halves; half63=1.0
  __shared__ uint4 sRhoHist[2][8][8]; // tail rho history; half63=1.0
  __shared__ u16 sZdc[2][NN][SP];     // bias + z/dz contribution (f16 bits)
  __shared__ u32 sZp[2][NN][5];
  __shared__ u32 sDZp[2][NN][5];
  __shared__ float sHas[2][NN];
  __shared__ u64 sRowM[NN];
  __shared__ u8 sConsL[NN][64];       // consumer lists (batch-independent)
  __shared__ int sConsCnt[NN];

  #define ROWB(E,I) ((char*)&sH4[(E)][(I)][0])
  const u32 BIASW = 0x3C000000u;      // halves {0, 1.0h}

  // ---- staging (raw reads + conversion) ----
  {
    if (tid < 64){
      u64 rowm = 0;
      for (int j=0;j<64;j++) rowm |= ((u64)(adj[tid*64+j]!=0))<<j;
      sRowM[tid] = rowm;
    }
    if (tid < 128){
      const int e = tid >> 6, n = tid & 63;
      sHas[e][n] = ldw(hasp_, (size_t)(bp+e)*NN + n, isbf);
    }
    for (int idx=tid; idx<2*65*9; idx+=256){
      uint4 v = {0,0,0,0};
      if ((idx % 9) == 7) v.w = BIASW;       // half63 = 1.0
      ((uint4*)sH4)[idx] = v;
    }
    if (tid < 16){ uint4 v={0,0,0,0}; if ((tid&7)==7) v.w = BIASW; ((uint4*)sRhoPad)[tid]=v; }
    if (tid < 128){ uint4 v={0,0,0,0}; if ((tid&7)==7) v.w = BIASW; ((uint4*)sRhoHist)[tid]=v; }
    for (int idx=tid; idx<2*NN*5; idx+=256){
      int e = idx/(NN*5), rem = idx%(NN*5), n2=rem/5, p2=rem%5;
      const size_t base = (size_t)(bp+e)*NN*SEX + n2*SEX + 2*p2;
      sZp [e][n2][p2] = pack2(ldw(zp_,  base, isbf), ldw(zp_,  base+1, isbf));
      sDZp[e][n2][p2] = pack2(ldw(dzp_, base, isbf), ldw(dzp_, base+1, isbf));
    }
  }
  __syncthreads();
  if (tid < 64){
    u64 cm = 0;
    if (bwd) for (int i2=0;i2<64;i2++) cm |= ((sRowM[i2]>>tid)&1ULL)<<i2;
    u64 m = bwd ? cm : sRowM[tid];          // consumers of node tid
    int c = 0;
    while (m){ int i2 = (int)__builtin_ctzll(m); m &= m-1; sConsL[tid][c++] = (u8)i2; }
    sConsCnt[tid] = c;
  }
  // zdc precompute: sZdc[e][t][uu] = bcat[uu] + Wz.z + Wdz.dz (bias folded).
  {
    const int uu = tid & 63;
    const int tw = tid >> 6;
    if (uu < SP){
      u32 wz[10];
      #pragma unroll
      for (int p=0;p<10;p++)
        wz[p] = pack2(ldw(Wcatp, uu*CATD + 60 + 2*p,     isbf),
                      ldw(Wcatp, uu*CATD + 60 + 2*p + 1, isbf));
      const float bb0 = ldw(bcatp, uu, isbf);
      for (int et=tw; et<2*NN; et+=4){
        const int e = et >> 6, t2 = et & 63;
        float c = bb0;
        #pragma unroll
        for (int p=0;p<5;p++){
          c = fdot2_(wz[p],   sZp [e][t2][p], c);
          c = fdot2_(wz[5+p], sDZp[e][t2][p], c);
        }
        sZdc[e][t2][uu] = __builtin_bit_cast(u16, (f16)c);
      }
    }
  }

  // ---- A fragments (wave w owns mt = w), shared across both elems ----
  f16x8 Ar[4], Az[4], Anh[2], Ani[2], Ac[2];
  {
    const int R = 16*w + ml;
    const bool rok = (R < SP);
    #pragma unroll
    for (int kt=0; kt<4; kt++){
      f16x8 vr, vz;
      #pragma unroll
      for (int j=0;j<8;j++){
        const int K = 32*kt + 8*q + j;
        float wr=0.f, wz2=0.f;
        if (rok){
          if (K < SP){ wr = ldw(Whhp, R*SP+K, isbf); wz2 = ldw(Whhp, (60+R)*SP+K, isbf); }
          else if (K >= 64 && K < 64+SP){ wr = ldw(Wihp, R*SP+(K-64), isbf); wz2 = ldw(Wihp, (60+R)*SP+(K-64), isbf); }
          else if (K == 127){ wr = ldw(bhhp,R,isbf)+ldw(bihp,R,isbf); wz2 = ldw(bhhp,60+R,isbf)+ldw(bihp,60+R,isbf); }
        }
        vr[j]=(f16)wr; vz[j]=(f16)wz2;
      }
      Ar[kt]=vr; Az[kt]=vz;
    }
    #pragma unroll
    for (int kt=0; kt<2; kt++){
      f16x8 vn, vi, vc;
      #pragma unroll
      for (int j=0;j<8;j++){
        const int K = 32*kt + 8*q + j;
        float wn=0.f, wi=0.f, wcv=0.f;
        if (rok){
          if (K < SP){ wn = ldw(Whhp,(120+R)*SP+K,isbf); wi = ldw(Wihp,(120+R)*SP+K,isbf); wcv = ldw(Wcatp,R*CATD+K,isbf); }
          else if (K == 63){ wn = ldw(bhhp,120+R,isbf); wi = ldw(bihp,120+R,isbf); }
        }
        vn[j]=(f16)wn; vi[j]=(f16)wi; vc[j]=(f16)wcv;
      }
      Anh[kt]=vn; Ani[kt]=vi; Ac[kt]=vc;
    }
  }
  __syncthreads();   // lists + zdc + LDS init visible

  // gates: GRU gate math + h read-modify-write, window [32w,32w+32) of rowb.
  auto gates = [&](f32x4 Dr, f32x4 Dz, f32x4 Dn, f32x4 Gn,
                   char* rowb, bool wr, float bl){
    char* rp = rowb + 32*w + 8*q;
    uint2 h2 = *(uint2*)rp;
    half2_t ha = __builtin_bit_cast(half2_t, h2.x);
    half2_t hb = __builtin_bit_cast(half2_t, h2.y);
    float hold[4] = { (float)ha[0], (float)ha[1], (float)hb[0], (float)hb[1] };
    float hw[4];
    #pragma unroll
    for (int reg=0;reg<4;reg++){
      float r_ = sigm(Dr[reg]);
      float zg = sigm(Dz[reg]);
      float nv = tanh_(Gn[reg] + r_*Dn[reg]);
      float hn_ = (1.f - zg)*nv + zg*hold[reg];
      hw[reg] = (bl != 0.f) ? hn_ : hold[reg];   // bl is exactly 0 or 1
    }
    if (wr && !(w==3 && q==3)){
      uint2 o; o.x = pack2(hw[0],hw[1]); o.y = pack2(hw[2],hw[3]);
      *(uint2*)rp = o;
    }
  };

  // full 11-MFMA pass (latent p>=2 groups + tail)
  auto fullpass = [&](f16x8 Bh0, f16x8 Bh1, f16x8 Br0, f16x8 Br1,
                      f32x4 Gn, char* rowb, bool wr, float bl){
    f32x4 Dr={0,0,0,0}, Dz={0,0,0,0}, Dn={0,0,0,0};
    Dr = mfma16(Ar[0], Bh0, Dr); Dr = mfma16(Ar[1], Bh1, Dr);
    Dr = mfma16(Ar[2], Br0, Dr); Dr = mfma16(Ar[3], Br1, Dr);
    Dz = mfma16(Az[0], Bh0, Dz); Dz = mfma16(Az[1], Bh1, Dz);
    Dz = mfma16(Az[2], Br0, Dz); Dz = mfma16(Az[3], Br1, Dz);
    Dn = mfma16(Anh[0], Bh0, Dn); Dn = mfma16(Anh[1], Bh1, Dn);
    gates(Dr, Dz, Dn, Gn, rowb, wr, bl);
  };

  // ---- 64 pipelined steps, 2 barriers each, 2 batch elems ----
  int t = bwd ? 63 : 0;
  const int dt = bwd ? -1 : 1;
  for (int s=0; s<64; s++, t+=dt){
    const int cnt = sConsCnt[t];
    const float bl0 = sHas[0][t];
    const float bl1 = sHas[1][t];
    const bool a0 = (bl0 != 0.f), a1 = (bl1 != 0.f);
    const int nact = (int)a0 + (int)a1;
    const bool act   = (cnt > 0) && (nact > 0);
    const bool fastp = act && (nact == 2) && (cnt <= 8);   // mixed single pass
    const bool snglp = act && (nact == 1);                 // one elem active
    const bool dualp = act && (nact == 2) && (cnt > 8);
    const bool g1d   = dualp && (cnt > 16);
    const bool g1s   = snglp && (cnt > 16);
    const int  ea    = a0 ? 0 : 1;
    const float bla  = a0 ? bl0 : bl1;

    // pre-R: consumer-row Bh preloads (reads only)
    int ci0 = 64, ci1 = 64, cim = 64;
    const int eh = ml >> 3;                     // fast-path elem per column
    f16x8 Bm0={}, Bm1={};
    f16x8 B0a={}, B1a={}, C0a={}, C1a={};       // snglp groups (elem ea)
    f16x8 Bh0e0={}, Bh1e0={}, Bh0e1={}, Bh1e1={};
    f16x8 Ch0e0={}, Ch1e0={}, Ch0e1={}, Ch1e1={};
    if (fastp){
      const int sl = ml & 7;
      cim = (sl < cnt) ? (int)sConsL[t][sl] : 64;
      Bm0 = bc16(sH4[eh][cim][q]);
      Bm1 = bc16(sH4[eh][cim][4+q]);
    } else if (snglp){
      ci0 = (ml < cnt) ? (int)sConsL[t][ml] : 64;
      B0a = bc16(sH4[ea][ci0][q]); B1a = bc16(sH4[ea][ci0][4+q]);
      if (g1s){
        ci1 = (16 + ml < cnt) ? (int)sConsL[t][16 + ml] : 64;
        C0a = bc16(sH4[ea][ci1][q]); C1a = bc16(sH4[ea][ci1][4+q]);
      }
    } else if (dualp){
      ci0 = (ml < cnt) ? (int)sConsL[t][ml] : 64;
      Bh0e0 = bc16(sH4[0][ci0][q]); Bh1e0 = bc16(sH4[0][ci0][4+q]);
      Bh0e1 = bc16(sH4[1][ci0][q]); Bh1e1 = bc16(sH4[1][ci0][4+q]);
      if (g1d){
        ci1 = (16 + ml < cnt) ? (int)sConsL[t][16 + ml] : 64;
        Ch0e0 = bc16(sH4[0][ci1][q]); Ch1e0 = bc16(sH4[0][ci1][4+q]);
        Ch0e1 = bc16(sH4[1][ci1][q]); Ch1e1 = bc16(sH4[1][ci1][4+q]);
      }
    }

    // phase 1 matvec, packed: cols 0-3 elem0, 4-7 elem1 (e = (ml>>2)&1).
    {
      const int em = (ml >> 2) & 1;
      const f16x8 Hm0 = bc16(sH4[em][t][q]);
      const f16x8 Hm1 = bc16(sH4[em][t][4+q]);
      f32x4 Rv = {0,0,0,0};
      Rv = mfma16(Ac[0], Hm0, Rv);
      Rv = mfma16(Ac[1], Hm1, Rv);
      const int row = 16*w + 4*q + (ml & 3);
      if (ml < 8 && row < SP){
        const int m3 = ml & 3;
        float vv = Rv[0];
        vv = (m3==1) ? Rv[1] : vv;
        vv = (m3==2) ? Rv[2] : vv;
        vv = (m3==3) ? Rv[3] : vv;
        vv += (float)__builtin_bit_cast(f16, sZdc[em][t][row]);
        if (!bwd) vv = tanh_(vv);
        *(f16*)((char*)&sRhoPad[em][0] + 2*row) = (f16)vv;
        const int slot = bwd ? t : (t - (NN-OO));
        if (slot >= 0 && slot < 8)
          *(f16*)((char*)&sRhoHist[em][slot][0] + 2*row) = (f16)vv;
        rho[((size_t)t*BATCH + bp + em)*SP + row] = vv;   // fire & forget
      }
    }
    __syncthreads();   // R: rho visible; pre-R h reads done before writes

    if (fastp){
      // mixed single pass: per-lane elem eh, consumer cim
      const f16x8 Brm0 = bc16(sRhoPad[eh][q]);
      const f16x8 Brm1 = bc16(sRhoPad[eh][4+q]);
      f32x4 Gn={0,0,0,0};
      Gn = mfma16(Ani[0], Brm0, Gn); Gn = mfma16(Ani[1], Brm1, Gn);
      f32x4 Dr={0,0,0,0}, Dz={0,0,0,0}, Dn={0,0,0,0};
      Dr = mfma16(Ar[2], Brm0, Dr); Dr = mfma16(Ar[3], Brm1, Dr);
      Dr = mfma16(Ar[0], Bm0,  Dr); Dr = mfma16(Ar[1], Bm1,  Dr);
      Dz = mfma16(Az[2], Brm0, Dz); Dz = mfma16(Az[3], Brm1, Dz);
      Dz = mfma16(Az[0], Bm0,  Dz); Dz = mfma16(Az[1], Bm1,  Dz);
      Dn = mfma16(Anh[0], Bm0, Dn); Dn = mfma16(Anh[1], Bm1, Dn);
      gates(Dr, Dz, Dn, Gn, ROWB(eh, cim), (ml & 7) < cnt, eh ? bl1 : bl0);
    } else if (snglp){
      // one elem active: single-elem passes (half the dual work)
      const f16x8 Br0 = bc16(sRhoPad[ea][q]);
      const f16x8 Br1 = bc16(sRhoPad[ea][4+q]);
      f32x4 Gn={0,0,0,0};
      Gn = mfma16(Ani[0], Br0, Gn); Gn = mfma16(Ani[1], Br1, Gn);
      f32x4 Pr={0,0,0,0};
      Pr = mfma16(Ar[2], Br0, Pr); Pr = mfma16(Ar[3], Br1, Pr);
      f32x4 Pz={0,0,0,0};
      Pz = mfma16(Az[2], Br0, Pz); Pz = mfma16(Az[3], Br1, Pz);
      {
        f32x4 Dr=Pr, Dz=Pz, Dn={0,0,0,0};
        Dr = mfma16(Ar[0], B0a, Dr);  Dr = mfma16(Ar[1], B1a, Dr);
        Dz = mfma16(Az[0], B0a, Dz);  Dz = mfma16(Az[1], B1a, Dz);
        Dn = mfma16(Anh[0], B0a, Dn); Dn = mfma16(Anh[1], B1a, Dn);
        gates(Dr, Dz, Dn, Gn, ROWB(ea,ci0), ml < cnt, bla);
      }
      if (g1s){
        f32x4 Dr=Pr, Dz=Pz, Dn={0,0,0,0};
        Dr = mfma16(Ar[0], C0a, Dr);  Dr = mfma16(Ar[1], C1a, Dr);
        Dz = mfma16(Az[0], C0a, Dz);  Dz = mfma16(Az[1], C1a, Dz);
        Dn = mfma16(Anh[0], C0a, Dn); Dn = mfma16(Anh[1], C1a, Dn);
        gates(Dr, Dz, Dn, Gn, ROWB(ea,ci1), 16 + ml < cnt, bla);
      }
      for (int p=2; 16*p < cnt; p++){       // latent (cnt<=32 for this input)
        const int idxp = 16*p + ml;
        const int ci = (idxp < cnt) ? (int)sConsL[t][idxp] : 64;
        fullpass(bc16(sH4[ea][ci][q]), bc16(sH4[ea][ci][4+q]),
                 Br0, Br1, Gn, ROWB(ea,ci), idxp < cnt, bla);
      }
    } else if (dualp){
      const f16x8 Br0e0 = bc16(sRhoPad[0][q]);
      const f16x8 Br1e0 = bc16(sRhoPad[0][4+q]);
      const f16x8 Br0e1 = bc16(sRhoPad[1][q]);
      const f16x8 Br1e1 = bc16(sRhoPad[1][4+q]);
      f32x4 Gn0={0,0,0,0}, Gn1={0,0,0,0};
      Gn0 = mfma16(Ani[0], Br0e0, Gn0);  Gn1 = mfma16(Ani[0], Br0e1, Gn1);
      Gn0 = mfma16(Ani[1], Br1e0, Gn0);  Gn1 = mfma16(Ani[1], Br1e1, Gn1);
      f32x4 Pr0={0,0,0,0}, Pr1={0,0,0,0};
      Pr0 = mfma16(Ar[2], Br0e0, Pr0);   Pr1 = mfma16(Ar[2], Br0e1, Pr1);
      Pr0 = mfma16(Ar[3], Br1e0, Pr0);   Pr1 = mfma16(Ar[3], Br1e1, Pr1);
      f32x4 Pz0={0,0,0,0}, Pz1={0,0,0,0};
      Pz0 = mfma16(Az[2], Br0e0, Pz0);   Pz1 = mfma16(Az[2], Br0e1, Pz1);
      Pz0 = mfma16(Az[3], Br1e0, Pz0);   Pz1 = mfma16(Az[3], Br1e1, Pz1);

      { // group 0, both elems interleaved
        f32x4 Dr0=Pr0, Dz0=Pz0, Dn0={0,0,0,0};
        f32x4 Dr1=Pr1, Dz1=Pz1, Dn1={0,0,0,0};
        Dr0 = mfma16(Ar[0], Bh0e0, Dr0);  Dr1 = mfma16(Ar[0], Bh0e1, Dr1);
        Dr0 = mfma16(Ar[1], Bh1e0, Dr0);  Dr1 = mfma16(Ar[1], Bh1e1, Dr1);
        Dz0 = mfma16(Az[0], Bh0e0, Dz0);  Dz1 = mfma16(Az[0], Bh0e1, Dz1);
        Dz0 = mfma16(Az[1], Bh1e0, Dz0);  Dz1 = mfma16(Az[1], Bh1e1, Dz1);
        Dn0 = mfma16(Anh[0], Bh0e0, Dn0); Dn1 = mfma16(Anh[0], Bh0e1, Dn1);
        Dn0 = mfma16(Anh[1], Bh1e0, Dn0); Dn1 = mfma16(Anh[1], Bh1e1, Dn1);
        gates(Dr0, Dz0, Dn0, Gn0, ROWB(0,ci0), ml < cnt, bl0);
        gates(Dr1, Dz1, Dn1, Gn1, ROWB(1,ci0), ml < cnt, bl1);
      }
      if (g1d){
        f32x4 Dr0=Pr0, Dz0=Pz0, Dn0={0,0,0,0};
        f32x4 Dr1=Pr1, Dz1=Pz1, Dn1={0,0,0,0};
        Dr0 = mfma16(Ar[0], Ch0e0, Dr0);  Dr1 = mfma16(Ar[0], Ch0e1, Dr1);
        Dr0 = mfma16(Ar[1], Ch1e0, Dr0);  Dr1 = mfma16(Ar[1], Ch1e1, Dr1);
        Dz0 = mfma16(Az[0], Ch0e0, Dz0);  Dz1 = mfma16(Az[0], Ch0e1, Dz1);
        Dz0 = mfma16(Az[1], Ch1e0, Dz0);  Dz1 = mfma16(Az[1], Ch1e1, Dz1);
        Dn0 = mfma16(Anh[0], Ch0e0, Dn0); Dn1 = mfma16(Anh[0], Ch0e1, Dn1);
        Dn0 = mfma16(Anh[1], Ch1e0, Dn0); Dn1 = mfma16(Anh[1], Ch1e1, Dn1);
        gates(Dr0, Dz0, Dn0, Gn0, ROWB(0,ci1), 16 + ml < cnt, bl0);
        gates(Dr1, Dz1, Dn1, Gn1, ROWB(1,ci1), 16 + ml < cnt, bl1);
      }
      for (int p=2; 16*p < cnt; p++){       // latent
        const int idxp = 16*p + ml;
        const int ci = (idxp < cnt) ? (int)sConsL[t][idxp] : 64;
        fullpass(bc16(sH4[0][ci][q]), bc16(sH4[0][ci][4+q]),
                 Br0e0, Br1e0, Gn0, ROWB(0,ci), idxp < cnt, bl0);
        fullpass(bc16(sH4[1][ci][q]), bc16(sH4[1][ci][4+q]),
                 Br0e1, Br1e1, Gn1, ROWB(1,ci), idxp < cnt, bl1);
      }
    }
    __syncthreads();   // C: h writes visible to next step's reads
  }

  // ---- alpha tail: 8 GRU steps, mixed-column packed (cols 0-7 elem0,
  // 8-15 elem1; per-lane e=ml>>3; writes at ml==0 / ml==8) ----
  for (int s2=0; s2<8; s2++){
    const int i = bwd ? (7 - s2) : (NN - OO + s2);
    const int slot = bwd ? i : (i - (NN-OO));
    const int et = ml >> 3;
    const f16x8 Th0 = bc16(sH4[et][64][q]);
    const f16x8 Th1 = bc16(sH4[et][64][4+q]);
    const f16x8 Tr0 = bc16(sRhoHist[et][slot][q]);
    const f16x8 Tr1 = bc16(sRhoHist[et][slot][4+q]);
    f32x4 Gt={0,0,0,0};
    Gt = mfma16(Ani[0], Tr0, Gt);
    Gt = mfma16(Ani[1], Tr1, Gt);
    __syncthreads();   // all waves' row-64 reads done before writes
    fullpass(Th0, Th1, Tr0, Tr1, Gt, ROWB(et,64), (ml&7)==0,
             et ? sHas[1][i] : sHas[0][i]);
    __syncthreads();   // writes visible to next tail step
  }
  if (tid < SP){
    alpha[(size_t)(bp  )*SP + tid] = (float)*(const f16*)(ROWB(0,64) + 2*tid);
    alpha[(size_t)(bp+1)*SP + tid] = (float)*(const f16*)(ROWB(1,64) + 2*tid);
  }
  #undef ROWB
}

// One block per batch element: psi + softmaxes, omega, value -> d_out.
// r21: own bf16 detect; weights read raw with conversion (conv_in gone).
__global__ __launch_bounds__(256, 1) void head_kernel(
  const void* hasp_, const void* Wa_, const void* ba_, const void* Wc_,
  const void* bc_, const void* Wu_, const void* bu_,
  float* __restrict__ ws, void* __restrict__ outp)
{
  const int b = blockIdx.x;
  const int tid = threadIdx.x;

  __shared__ int sIsBf;
  if (tid < 64){
    const u32* hw_ = (const u32*)hasp_;
    int f = 0;
    #pragma unroll
    for (int k=0;k<4;k++) f |= (hw_[tid*4 + k] == 0x3F803F80u) ? 1 : 0;
    u64 m = __ballot(f != 0);
    if (tid == 0) sIsBf = (m != 0ULL) ? 1 : 0;
  }
  __syncthreads();
  const int isbf = sIsBf;

  const float* rhoF   = ws + OFF_RHOF;
  const float* rhoB   = ws + OFF_RHOB;
  const float* alphaF = ws + OFF_ALF;
  const float* alphaB = ws + OFF_ALB;

  __shared__ float sF[NN][122];    // 488B stride: float2-aligned
  __shared__ float sAB[120];
  __shared__ float sWu[NR*120];
  __shared__ float sHasR[NN];
  __shared__ float sPsi[NR][NN];
  __shared__ float sOm[NA];

  auto wout = [&](int idx, float v){
    if (isbf) ((u16*)outp)[idx] = f2bf(v);
    else      ((float*)outp)[idx] = v;
  };

  for (int idx=tid; idx<NN*SP; idx+=256){
    int n = idx/SP, s = idx%SP;
    sF[n][s]    = rhoF[((size_t)n*BATCH + b)*SP + s];
    sF[n][60+s] = rhoB[((size_t)n*BATCH + b)*SP + s];
  }
  for (int idx=tid; idx<120; idx+=256)
    sAB[idx] = (idx<60) ? alphaF[(size_t)b*SP + idx] : alphaB[(size_t)b*SP + idx-60];
  for (int idx=tid; idx<NR*120; idx+=256) sWu[idx] = ldw(Wu_, idx, isbf);
  for (int idx=tid; idx<NN; idx+=256) sHasR[idx] = ldw(hasp_, (size_t)b*NN + idx, isbf);
  __syncthreads();

  for (int idx=tid; idx<NR*NN; idx+=256){
    int r = idx/NN, n = idx%NN;
    const float2* fn = (const float2*)&sF[n][0];
    const float2* wr = (const float2*)&sWu[r*120];
    float acc = ldw(bu_, r, isbf);
    #pragma unroll 6
    for (int s2=0;s2<60;s2++){
      float2 a = fn[s2], c = wr[s2];
      acc += a.x*c.x;
      acc += a.y*c.y;
    }
    sPsi[r][n] = (sHasR[n] != 0.f) ? acc : -60.f;
  }
  if (tid >= 64 && tid < 64+NA){
    int a = tid - 64;
    float acc = ldw(ba_, a, isbf);
    for (int s=0;s<120;s++) acc += sAB[s]*ldw(Wa_, a*120+s, isbf);
    sOm[a] = acc;
  }
  if (tid == 70){
    float acc = ldw(bc_, 0, isbf);
    for (int s=0;s<120;s++) acc += sAB[s]*ldw(Wc_, s, isbf);
    wout(2560 + BATCH*NR*NN + b, acc);                 // value
  }
  __syncthreads();

  if (tid < NR*32){
    const int r = tid >> 5, l = tid & 31;
    float v0 = sPsi[r][l], v1 = sPsi[r][l+32];
    float m = fmaxf(v0, v1);
    #pragma unroll
    for (int o=16;o>0;o>>=1) m = fmaxf(m, __shfl_xor(m, o, 64));
    float e0 = __expf(v0 - m), e1 = __expf(v1 - m);
    float ssum = e0 + e1;
    #pragma unroll
    for (int o=16;o>0;o>>=1) ssum += __shfl_xor(ssum, o, 64);
    float rinv = 1.f/ssum;
    wout(2560 + (size_t)b*NR*NN + r*NN + l,    e0*rinv);   // role_prob
    wout(2560 + (size_t)b*NR*NN + r*NN + l+32, e1*rinv);
  }
  if (tid == 224){   // idle lane in the softmax phase
    float m = -1e30f;
    for (int a=0;a<NA;a++) m = fmaxf(m, sOm[a]);
    float e[NA]; float ssum = 0.f;
    for (int a=0;a<NA;a++){ e[a] = __expf(sOm[a]-m); ssum += e[a]; }
    for (int a=0;a<NA;a++) wout(b*NA + a, e[a]/ssum);  // instr_prob
  }
}

extern "C" void kernel_launch(void* const* d_in, const int* in_sizes, int n_in,
                              void* d_out, int out_size, void* d_ws, size_t ws_size,
                              hipStream_t stream)
{
  const int* adj = (const int*)d_in[3];
  float* ws = (float*)d_ws;

  dir_kernel<<<512, 256, 0, stream>>>(
      adj, d_in[0], d_in[1], d_in[2],
      d_in[4], d_in[5], d_in[6], d_in[7],
      d_in[8], d_in[9], d_in[10], d_in[11],
      d_in[12], d_in[13], d_in[14], d_in[15], ws);

  head_kernel<<<512, 256, 0, stream>>>(
      d_in[2], d_in[16], d_in[17], d_in[18], d_in[19],
      d_in[20], d_in[21], ws, d_out);
}

// Round 14
// 248.972 us; speedup vs baseline: 1.0964x; 1.0058x over previous
//
#include <hip/hip_runtime.h>
#include <hip/hip_bf16.h>

#define NN 64
#define BATCH 512
#define SP 60
#define SG 180
#define SEX 10
#define CATD 80
#define NA 5
#define NR 7
#define OO 8
#define II 8

typedef unsigned long long u64;
typedef unsigned short u16;
typedef unsigned int u32;
typedef unsigned char u8;

// ---- workspace layout (float offsets; rho/alpha only now) ----
#define OFF_RHOF  743344
#define OFF_RHOB  (OFF_RHOF + 1966080)
#define OFF_ALF   (OFF_RHOB + 1966080)
#define OFF_ALB   (OFF_ALF + 30720)

typedef _Float16 f16;
typedef _Float16 half2_t __attribute__((ext_vector_type(2)));
typedef _Float16 f16x8 __attribute__((ext_vector_type(8)));
typedef float f32x4 __attribute__((ext_vector_type(4)));

__device__ __forceinline__ float us2f(u16 v){
  return __uint_as_float(((u32)v) << 16);
}
__device__ __forceinline__ u16 f2bf(float f){
  __hip_bfloat16 h = __float2bfloat16(f);
  return *reinterpret_cast<u16*>(&h);
}
__device__ __forceinline__ float rcp_(float x){ return __builtin_amdgcn_rcpf(x); }
__device__ __forceinline__ float sigm(float x){
  return rcp_(1.f + __expf(-x));
}
__device__ __forceinline__ float tanh_(float x){
  float e = __expf(2.f*fabsf(x));
  float t = 1.f - 2.f*rcp_(e + 1.f);
  return copysignf(t, x);
}
__device__ __forceinline__ u32 pack2(float a, float b){
  half2_t h; h[0] = (f16)a; h[1] = (f16)b;
  return __builtin_bit_cast(u32, h);
}
__device__ __forceinline__ float fdot2_(u32 a, u32 b, float c){
  return __builtin_amdgcn_fdot2(__builtin_bit_cast(half2_t, a),
                                __builtin_bit_cast(half2_t, b), c, false);
}
__device__ __forceinline__ f16x8 bc16(uint4 v){ return __builtin_bit_cast(f16x8, v); }
__device__ __forceinline__ f32x4 mfma16(f16x8 a, f16x8 b, f32x4 c){
  return __builtin_amdgcn_mfma_f32_16x16x32_f16(a, b, c, 0, 0, 0);
}
// raw load with optional bf16 conversion (bit-identical to old conv_in path)
__device__ __forceinline__ float ldw(const void* p, size_t i, int isbf){
  return isbf ? us2f(((const u16*)p)[i]) : ((const float*)p)[i];
}

// r24 == r21 (best measured dir: 137.9us). r23's LDS cut was pointless:
// grid = 512 blocks on 256 CUs = 2 blocks/CU AVAILABLE -- co-residency is
// grid-limited, not LDS-limited, so f16 sZdc only added unpack cost.
// Config: 2 elems/block (ILP), conv_in eliminated (raw reads + inline
// conversion), mixed-column fast path (cnt<=8), snglp path (1 elem
// active), packed alpha tail, 2 barriers/step.
__global__ __launch_bounds__(256, 2) void dir_kernel(
  const int* __restrict__ adj, const void* zp_, const void* dzp_,
  const void* hasp_,
  const void* WihF_, const void* WhhF_, const void* bihF_, const void* bhhF_,
  const void* WihB_, const void* WhhB_, const void* bihB_, const void* bhhB_,
  const void* Wf_, const void* bf_, const void* Wb_, const void* bb_,
  float* __restrict__ ws)
{
  const int tid = threadIdx.x;
  const int w   = tid >> 6;         // wave id (0..3) == row tile mt
  const int u   = tid & 63;         // lane
  const int ml  = u & 15;           // MFMA col (consumer slot)
  const int q   = u >> 4;           // MFMA quad
  const int bid = blockIdx.x;
  const int bwd = bid >> 8;
  const int bp  = (bid & 255) << 1; // batch pair base {bp, bp+1}

  __shared__ int sIsBf;
  if (tid < 64){
    const u32* hw_ = (const u32*)hasp_;
    int f = 0;
    #pragma unroll
    for (int k=0;k<4;k++) f |= (hw_[tid*4 + k] == 0x3F803F80u) ? 1 : 0;
    u64 m = __ballot(f != 0);
    if (tid == 0) sIsBf = (m != 0ULL) ? 1 : 0;
  }
  __syncthreads();
  const int isbf = sIsBf;

  const void* Wihp  = bwd ? WihB_ : WihF_;
  const void* Whhp  = bwd ? WhhB_ : WhhF_;
  const void* bihp  = bwd ? bihB_ : bihF_;
  const void* bhhp  = bwd ? bhhB_ : bhhF_;
  const void* Wcatp = bwd ? Wb_   : Wf_;
  const void* bcatp = bwd ? bb_   : bf_;
  float* rho   = ws + (bwd ? OFF_RHOB : OFF_RHOF);  // [64][512][60]
  float* alpha = ws + (bwd ? OFF_ALB  : OFF_ALF);   // [512][60]

  __shared__ uint4 sH4[2][65][9];     // h rows per elem; half63=1.0 (bias ch)
  __shared__ uint4 sRhoPad[2][8];     // rho_t halves; half63=1.0
  __shared__ uint4 sRhoHist[2][8][8]; // tail rho history; half63=1.0
  __shared__ float sZdc[2][NN][SP];   // precomputed bias + z/dz contribution
  __shared__ u32 sZp[2][NN][5];
  __shared__ u32 sDZp[2][NN][5];
  __shared__ float sHas[2][NN];
  __shared__ u64 sRowM[NN];
  __shared__ u8 sConsL[NN][64];       // consumer lists (batch-independent)
  __shared__ int sConsCnt[NN];

  #define ROWB(E,I) ((char*)&sH4[(E)][(I)][0])
  const u32 BIASW = 0x3C000000u;      // halves {0, 1.0h}

  // ---- staging (raw reads + conversion) ----
  {
    if (tid < 64){
      u64 rowm = 0;
      for (int j=0;j<64;j++) rowm |= ((u64)(adj[tid*64+j]!=0))<<j;
      sRowM[tid] = rowm;
    }
    if (tid < 128){
      const int e = tid >> 6, n = tid & 63;
      sHas[e][n] = ldw(hasp_, (size_t)(bp+e)*NN + n, isbf);
    }
    for (int idx=tid; idx<2*65*9; idx+=256){
      uint4 v = {0,0,0,0};
      if ((idx % 9) == 7) v.w = BIASW;       // half63 = 1.0
      ((uint4*)sH4)[idx] = v;
    }
    if (tid < 16){ uint4 v={0,0,0,0}; if ((tid&7)==7) v.w = BIASW; ((uint4*)sRhoPad)[tid]=v; }
    if (tid < 128){ uint4 v={0,0,0,0}; if ((tid&7)==7) v.w = BIASW; ((uint4*)sRhoHist)[tid]=v; }
    for (int idx=tid; idx<2*NN*5; idx+=256){
      int e = idx/(NN*5), rem = idx%(NN*5), n2=rem/5, p2=rem%5;
      const size_t base = (size_t)(bp+e)*NN*SEX + n2*SEX + 2*p2;
      sZp [e][n2][p2] = pack2(ldw(zp_,  base, isbf), ldw(zp_,  base+1, isbf));
      sDZp[e][n2][p2] = pack2(ldw(dzp_, base, isbf), ldw(dzp_, base+1, isbf));
    }
  }
  __syncthreads();
  if (tid < 64){
    u64 cm = 0;
    if (bwd) for (int i2=0;i2<64;i2++) cm |= ((sRowM[i2]>>tid)&1ULL)<<i2;
    u64 m = bwd ? cm : sRowM[tid];          // consumers of node tid
    int c = 0;
    while (m){ int i2 = (int)__builtin_ctzll(m); m &= m-1; sConsL[tid][c++] = (u8)i2; }
    sConsCnt[tid] = c;
  }
  // zdc precompute: sZdc[e][t][uu] = bcat[uu] + Wz.z + Wdz.dz (bias folded).
  {
    const int uu = tid & 63;
    const int tw = tid >> 6;
    if (uu < SP){
      u32 wz[10];
      #pragma unroll
      for (int p=0;p<10;p++)
        wz[p] = pack2(ldw(Wcatp, uu*CATD + 60 + 2*p,     isbf),
                      ldw(Wcatp, uu*CATD + 60 + 2*p + 1, isbf));
      const float bb0 = ldw(bcatp, uu, isbf);
      for (int et=tw; et<2*NN; et+=4){
        const int e = et >> 6, t2 = et & 63;
        float c = bb0;
        #pragma unroll
        for (int p=0;p<5;p++){
          c = fdot2_(wz[p],   sZp [e][t2][p], c);
          c = fdot2_(wz[5+p], sDZp[e][t2][p], c);
        }
        sZdc[e][t2][uu] = c;
      }
    }
  }

  // ---- A fragments (wave w owns mt = w), shared across both elems ----
  f16x8 Ar[4], Az[4], Anh[2], Ani[2], Ac[2];
  {
    const int R = 16*w + ml;
    const bool rok = (R < SP);
    #pragma unroll
    for (int kt=0; kt<4; kt++){
      f16x8 vr, vz;
      #pragma unroll
      for (int j=0;j<8;j++){
        const int K = 32*kt + 8*q + j;
        float wr=0.f, wz2=0.f;
        if (rok){
          if (K < SP){ wr = ldw(Whhp, R*SP+K, isbf); wz2 = ldw(Whhp, (60+R)*SP+K, isbf); }
          else if (K >= 64 && K < 64+SP){ wr = ldw(Wihp, R*SP+(K-64), isbf); wz2 = ldw(Wihp, (60+R)*SP+(K-64), isbf); }
          else if (K == 127){ wr = ldw(bhhp,R,isbf)+ldw(bihp,R,isbf); wz2 = ldw(bhhp,60+R,isbf)+ldw(bihp,60+R,isbf); }
        }
        vr[j]=(f16)wr; vz[j]=(f16)wz2;
      }
      Ar[kt]=vr; Az[kt]=vz;
    }
    #pragma unroll
    for (int kt=0; kt<2; kt++){
      f16x8 vn, vi, vc;
      #pragma unroll
      for (int j=0;j<8;j++){
        const int K = 32*kt + 8*q + j;
        float wn=0.f, wi=0.f, wcv=0.f;
        if (rok){
          if (K < SP){ wn = ldw(Whhp,(120+R)*SP+K,isbf); wi = ldw(Wihp,(120+R)*SP+K,isbf); wcv = ldw(Wcatp,R*CATD+K,isbf); }
          else if (K == 63){ wn = ldw(bhhp,120+R,isbf); wi = ldw(bihp,120+R,isbf); }
        }
        vn[j]=(f16)wn; vi[j]=(f16)wi; vc[j]=(f16)wcv;
      }
      Anh[kt]=vn; Ani[kt]=vi; Ac[kt]=vc;
    }
  }
  __syncthreads();   // lists + zdc + LDS init visible

  // gates: GRU gate math + h read-modify-write, window [32w,32w+32) of rowb.
  auto gates = [&](f32x4 Dr, f32x4 Dz, f32x4 Dn, f32x4 Gn,
                   char* rowb, bool wr, float bl){
    char* rp = rowb + 32*w + 8*q;
    uint2 h2 = *(uint2*)rp;
    half2_t ha = __builtin_bit_cast(half2_t, h2.x);
    half2_t hb = __builtin_bit_cast(half2_t, h2.y);
    float hold[4] = { (float)ha[0], (float)ha[1], (float)hb[0], (float)hb[1] };
    float hw[4];
    #pragma unroll
    for (int reg=0;reg<4;reg++){
      float r_ = sigm(Dr[reg]);
      float zg = sigm(Dz[reg]);
      float nv = tanh_(Gn[reg] + r_*Dn[reg]);
      float hn_ = (1.f - zg)*nv + zg*hold[reg];
      hw[reg] = (bl != 0.f) ? hn_ : hold[reg];   // bl is exactly 0 or 1
    }
    if (wr && !(w==3 && q==3)){
      uint2 o; o.x = pack2(hw[0],hw[1]); o.y = pack2(hw[2],hw[3]);
      *(uint2*)rp = o;
    }
  };

  // full 11-MFMA pass (latent p>=2 groups + tail)
  auto fullpass = [&](f16x8 Bh0, f16x8 Bh1, f16x8 Br0, f16x8 Br1,
                      f32x4 Gn, char* rowb, bool wr, float bl){
    f32x4 Dr={0,0,0,0}, Dz={0,0,0,0}, Dn={0,0,0,0};
    Dr = mfma16(Ar[0], Bh0, Dr); Dr = mfma16(Ar[1], Bh1, Dr);
    Dr = mfma16(Ar[2], Br0, Dr); Dr = mfma16(Ar[3], Br1, Dr);
    Dz = mfma16(Az[0], Bh0, Dz); Dz = mfma16(Az[1], Bh1, Dz);
    Dz = mfma16(Az[2], Br0, Dz); Dz = mfma16(Az[3], Br1, Dz);
    Dn = mfma16(Anh[0], Bh0, Dn); Dn = mfma16(Anh[1], Bh1, Dn);
    gates(Dr, Dz, Dn, Gn, rowb, wr, bl);
  };

  // ---- 64 pipelined steps, 2 barriers each, 2 batch elems ----
  int t = bwd ? 63 : 0;
  const int dt = bwd ? -1 : 1;
  for (int s=0; s<64; s++, t+=dt){
    const int cnt = sConsCnt[t];
    const float bl0 = sHas[0][t];
    const float bl1 = sHas[1][t];
    const bool a0 = (bl0 != 0.f), a1 = (bl1 != 0.f);
    const int nact = (int)a0 + (int)a1;
    const bool act   = (cnt > 0) && (nact > 0);
    const bool fastp = act && (nact == 2) && (cnt <= 8);   // mixed single pass
    const bool snglp = act && (nact == 1);                 // one elem active
    const bool dualp = act && (nact == 2) && (cnt > 8);
    const bool g1d   = dualp && (cnt > 16);
    const bool g1s   = snglp && (cnt > 16);
    const int  ea    = a0 ? 0 : 1;
    const float bla  = a0 ? bl0 : bl1;

    // pre-R: consumer-row Bh preloads (reads only)
    int ci0 = 64, ci1 = 64, cim = 64;
    const int eh = ml >> 3;                     // fast-path elem per column
    f16x8 Bm0={}, Bm1={};
    f16x8 B0a={}, B1a={}, C0a={}, C1a={};       // snglp groups (elem ea)
    f16x8 Bh0e0={}, Bh1e0={}, Bh0e1={}, Bh1e1={};
    f16x8 Ch0e0={}, Ch1e0={}, Ch0e1={}, Ch1e1={};
    if (fastp){
      const int sl = ml & 7;
      cim = (sl < cnt) ? (int)sConsL[t][sl] : 64;
      Bm0 = bc16(sH4[eh][cim][q]);
      Bm1 = bc16(sH4[eh][cim][4+q]);
    } else if (snglp){
      ci0 = (ml < cnt) ? (int)sConsL[t][ml] : 64;
      B0a = bc16(sH4[ea][ci0][q]); B1a = bc16(sH4[ea][ci0][4+q]);
      if (g1s){
        ci1 = (16 + ml < cnt) ? (int)sConsL[t][16 + ml] : 64;
        C0a = bc16(sH4[ea][ci1][q]); C1a = bc16(sH4[ea][ci1][4+q]);
      }
    } else if (dualp){
      ci0 = (ml < cnt) ? (int)sConsL[t][ml] : 64;
      Bh0e0 = bc16(sH4[0][ci0][q]); Bh1e0 = bc16(sH4[0][ci0][4+q]);
      Bh0e1 = bc16(sH4[1][ci0][q]); Bh1e1 = bc16(sH4[1][ci0][4+q]);
      if (g1d){
        ci1 = (16 + ml < cnt) ? (int)sConsL[t][16 + ml] : 64;
        Ch0e0 = bc16(sH4[0][ci1][q]); Ch1e0 = bc16(sH4[0][ci1][4+q]);
        Ch0e1 = bc16(sH4[1][ci1][q]); Ch1e1 = bc16(sH4[1][ci1][4+q]);
      }
    }

    // phase 1 matvec, packed: cols 0-3 elem0, 4-7 elem1 (e = (ml>>2)&1).
    {
      const int em = (ml >> 2) & 1;
      const f16x8 Hm0 = bc16(sH4[em][t][q]);
      const f16x8 Hm1 = bc16(sH4[em][t][4+q]);
      f32x4 Rv = {0,0,0,0};
      Rv = mfma16(Ac[0], Hm0, Rv);
      Rv = mfma16(Ac[1], Hm1, Rv);
      const int row = 16*w + 4*q + (ml & 3);
      if (ml < 8 && row < SP){
        const int m3 = ml & 3;
        float vv = Rv[0];
        vv = (m3==1) ? Rv[1] : vv;
        vv = (m3==2) ? Rv[2] : vv;
        vv = (m3==3) ? Rv[3] : vv;
        vv += sZdc[em][t][row];
        if (!bwd) vv = tanh_(vv);
        *(f16*)((char*)&sRhoPad[em][0] + 2*row) = (f16)vv;
        const int slot = bwd ? t : (t - (NN-OO));
        if (slot >= 0 && slot < 8)
          *(f16*)((char*)&sRhoHist[em][slot][0] + 2*row) = (f16)vv;
        rho[((size_t)t*BATCH + bp + em)*SP + row] = vv;   // fire & forget
      }
    }
    __syncthreads();   // R: rho visible; pre-R h reads done before writes

    if (fastp){
      // mixed single pass: per-lane elem eh, consumer cim
      const f16x8 Brm0 = bc16(sRhoPad[eh][q]);
      const f16x8 Brm1 = bc16(sRhoPad[eh][4+q]);
      f32x4 Gn={0,0,0,0};
      Gn = mfma16(Ani[0], Brm0, Gn); Gn = mfma16(Ani[1], Brm1, Gn);
      f32x4 Dr={0,0,0,0}, Dz={0,0,0,0}, Dn={0,0,0,0};
      Dr = mfma16(Ar[2], Brm0, Dr); Dr = mfma16(Ar[3], Brm1, Dr);
      Dr = mfma16(Ar[0], Bm0,  Dr); Dr = mfma16(Ar[1], Bm1,  Dr);
      Dz = mfma16(Az[2], Brm0, Dz); Dz = mfma16(Az[3], Brm1, Dz);
      Dz = mfma16(Az[0], Bm0,  Dz); Dz = mfma16(Az[1], Bm1,  Dz);
      Dn = mfma16(Anh[0], Bm0, Dn); Dn = mfma16(Anh[1], Bm1, Dn);
      gates(Dr, Dz, Dn, Gn, ROWB(eh, cim), (ml & 7) < cnt, eh ? bl1 : bl0);
    } else if (snglp){
      // one elem active: single-elem passes (half the dual work)
      const f16x8 Br0 = bc16(sRhoPad[ea][q]);
      const f16x8 Br1 = bc16(sRhoPad[ea][4+q]);
      f32x4 Gn={0,0,0,0};
      Gn = mfma16(Ani[0], Br0, Gn); Gn = mfma16(Ani[1], Br1, Gn);
      f32x4 Pr={0,0,0,0};
      Pr = mfma16(Ar[2], Br0, Pr); Pr = mfma16(Ar[3], Br1, Pr);
      f32x4 Pz={0,0,0,0};
      Pz = mfma16(Az[2], Br0, Pz); Pz = mfma16(Az[3], Br1, Pz);
      {
        f32x4 Dr=Pr, Dz=Pz, Dn={0,0,0,0};
        Dr = mfma16(Ar[0], B0a, Dr);  Dr = mfma16(Ar[1], B1a, Dr);
        Dz = mfma16(Az[0], B0a, Dz);  Dz = mfma16(Az[1], B1a, Dz);
        Dn = mfma16(Anh[0], B0a, Dn); Dn = mfma16(Anh[1], B1a, Dn);
        gates(Dr, Dz, Dn, Gn, ROWB(ea,ci0), ml < cnt, bla);
      }
      if (g1s){
        f32x4 Dr=Pr, Dz=Pz, Dn={0,0,0,0};
        Dr = mfma16(Ar[0], C0a, Dr);  Dr = mfma16(Ar[1], C1a, Dr);
        Dz = mfma16(Az[0], C0a, Dz);  Dz = mfma16(Az[1], C1a, Dz);
        Dn = mfma16(Anh[0], C0a, Dn); Dn = mfma16(Anh[1], C1a, Dn);
        gates(Dr, Dz, Dn, Gn, ROWB(ea,ci1), 16 + ml < cnt, bla);
      }
      for (int p=2; 16*p < cnt; p++){       // latent (cnt<=32 for this input)
        const int idxp = 16*p + ml;
        const int ci = (idxp < cnt) ? (int)sConsL[t][idxp] : 64;
        fullpass(bc16(sH4[ea][ci][q]), bc16(sH4[ea][ci][4+q]),
                 Br0, Br1, Gn, ROWB(ea,ci), idxp < cnt, bla);
      }
    } else if (dualp){
      const f16x8 Br0e0 = bc16(sRhoPad[0][q]);
      const f16x8 Br1e0 = bc16(sRhoPad[0][4+q]);
      const f16x8 Br0e1 = bc16(sRhoPad[1][q]);
      const f16x8 Br1e1 = bc16(sRhoPad[1][4+q]);
      f32x4 Gn0={0,0,0,0}, Gn1={0,0,0,0};
      Gn0 = mfma16(Ani[0], Br0e0, Gn0);  Gn1 = mfma16(Ani[0], Br0e1, Gn1);
      Gn0 = mfma16(Ani[1], Br1e0, Gn0);  Gn1 = mfma16(Ani[1], Br1e1, Gn1);
      f32x4 Pr0={0,0,0,0}, Pr1={0,0,0,0};
      Pr0 = mfma16(Ar[2], Br0e0, Pr0);   Pr1 = mfma16(Ar[2], Br0e1, Pr1);
      Pr0 = mfma16(Ar[3], Br1e0, Pr0);   Pr1 = mfma16(Ar[3], Br1e1, Pr1);
      f32x4 Pz0={0,0,0,0}, Pz1={0,0,0,0};
      Pz0 = mfma16(Az[2], Br0e0, Pz0);   Pz1 = mfma16(Az[2], Br0e1, Pz1);
      Pz0 = mfma16(Az[3], Br1e0, Pz0);   Pz1 = mfma16(Az[3], Br1e1, Pz1);

      { // group 0, both elems interleaved
        f32x4 Dr0=Pr0, Dz0=Pz0, Dn0={0,0,0,0};
        f32x4 Dr1=Pr1, Dz1=Pz1, Dn1={0,0,0,0};
        Dr0 = mfma16(Ar[0], Bh0e0, Dr0);  Dr1 = mfma16(Ar[0], Bh0e1, Dr1);
        Dr0 = mfma16(Ar[1], Bh1e0, Dr0);  Dr1 = mfma16(Ar[1], Bh1e1, Dr1);
        Dz0 = mfma16(Az[0], Bh0e0, Dz0);  Dz1 = mfma16(Az[0], Bh0e1, Dz1);
        Dz0 = mfma16(Az[1], Bh1e0, Dz0);  Dz1 = mfma16(Az[1], Bh1e1, Dz1);
        Dn0 = mfma16(Anh[0], Bh0e0, Dn0); Dn1 = mfma16(Anh[0], Bh0e1, Dn1);
        Dn0 = mfma16(Anh[1], Bh1e0, Dn0); Dn1 = mfma16(Anh[1], Bh1e1, Dn1);
        gates(Dr0, Dz0, Dn0, Gn0, ROWB(0,ci0), ml < cnt, bl0);
        gates(Dr1, Dz1, Dn1, Gn1, ROWB(1,ci0), ml < cnt, bl1);
      }
      if (g1d){
        f32x4 Dr0=Pr0, Dz0=Pz0, Dn0={0,0,0,0};
        f32x4 Dr1=Pr1, Dz1=Pz1, Dn1={0,0,0,0};
        Dr0 = mfma16(Ar[0], Ch0e0, Dr0);  Dr1 = mfma16(Ar[0], Ch0e1, Dr1);
        Dr0 = mfma16(Ar[1], Ch1e0, Dr0);  Dr1 = mfma16(Ar[1], Ch1e1, Dr1);
        Dz0 = mfma16(Az[0], Ch0e0, Dz0);  Dz1 = mfma16(Az[0], Ch0e1, Dz1);
        Dz0 = mfma16(Az[1], Ch1e0, Dz0);  Dz1 = mfma16(Az[1], Ch1e1, Dz1);
        Dn0 = mfma16(Anh[0], Ch0e0, Dn0); Dn1 = mfma16(Anh[0], Ch0e1, Dn1);
        Dn0 = mfma16(Anh[1], Ch1e0, Dn0); Dn1 = mfma16(Anh[1], Ch1e1, Dn1);
        gates(Dr0, Dz0, Dn0, Gn0, ROWB(0,ci1), 16 + ml < cnt, bl0);
        gates(Dr1, Dz1, Dn1, Gn1, ROWB(1,ci1), 16 + ml < cnt, bl1);
      }
      for (int p=2; 16*p < cnt; p++){       // latent
        const int idxp = 16*p + ml;
        const int ci = (idxp < cnt) ? (int)sConsL[t][idxp] : 64;
        fullpass(bc16(sH4[0][ci][q]), bc16(sH4[0][ci][4+q]),
                 Br0e0, Br1e0, Gn0, ROWB(0,ci), idxp < cnt, bl0);
        fullpass(bc16(sH4[1][ci][q]), bc16(sH4[1][ci][4+q]),
                 Br0e1, Br1e1, Gn1, ROWB(1,ci), idxp < cnt, bl1);
      }
    }
    __syncthreads();   // C: h writes visible to next step's reads
  }

  // ---- alpha tail: 8 GRU steps, mixed-column packed (cols 0-7 elem0,
  // 8-15 elem1; per-lane e=ml>>3; writes at ml==0 / ml==8) ----
  for (int s2=0; s2<8; s2++){
    const int i = bwd ? (7 - s2) : (NN - OO + s2);
    const int slot = bwd ? i : (i - (NN-OO));
    const int et = ml >> 3;
    const f16x8 Th0 = bc16(sH4[et][64][q]);
    const f16x8 Th1 = bc16(sH4[et][64][4+q]);
    const f16x8 Tr0 = bc16(sRhoHist[et][slot][q]);
    const f16x8 Tr1 = bc16(sRhoHist[et][slot][4+q]);
    f32x4 Gt={0,0,0,0};
    Gt = mfma16(Ani[0], Tr0, Gt);
    Gt = mfma16(Ani[1], Tr1, Gt);
    __syncthreads();   // all waves' row-64 reads done before writes
    fullpass(Th0, Th1, Tr0, Tr1, Gt, ROWB(et,64), (ml&7)==0,
             et ? sHas[1][i] : sHas[0][i]);
    __syncthreads();   // writes visible to next tail step
  }
  if (tid < SP){
    alpha[(size_t)(bp  )*SP + tid] = (float)*(const f16*)(ROWB(0,64) + 2*tid);
    alpha[(size_t)(bp+1)*SP + tid] = (float)*(const f16*)(ROWB(1,64) + 2*tid);
  }
  #undef ROWB
}

// One block per batch element: psi + softmaxes, omega, value -> d_out.
// r21: own bf16 detect; weights read raw with conversion (conv_in gone).
__global__ __launch_bounds__(256, 1) void head_kernel(
  const void* hasp_, const void* Wa_, const void* ba_, const void* Wc_,
  const void* bc_, const void* Wu_, const void* bu_,
  float* __restrict__ ws, void* __restrict__ outp)
{
  const int b = blockIdx.x;
  const int tid = threadIdx.x;

  __shared__ int sIsBf;
  if (tid < 64){
    const u32* hw_ = (const u32*)hasp_;
    int f = 0;
    #pragma unroll
    for (int k=0;k<4;k++) f |= (hw_[tid*4 + k] == 0x3F803F80u) ? 1 : 0;
    u64 m = __ballot(f != 0);
    if (tid == 0) sIsBf = (m != 0ULL) ? 1 : 0;
  }
  __syncthreads();
  const int isbf = sIsBf;

  const float* rhoF   = ws + OFF_RHOF;
  const float* rhoB   = ws + OFF_RHOB;
  const float* alphaF = ws + OFF_ALF;
  const float* alphaB = ws + OFF_ALB;

  __shared__ float sF[NN][122];    // 488B stride: float2-aligned
  __shared__ float sAB[120];
  __shared__ float sWu[NR*120];
  __shared__ float sHasR[NN];
  __shared__ float sPsi[NR][NN];
  __shared__ float sOm[NA];

  auto wout = [&](int idx, float v){
    if (isbf) ((u16*)outp)[idx] = f2bf(v);
    else      ((float*)outp)[idx] = v;
  };

  for (int idx=tid; idx<NN*SP; idx+=256){
    int n = idx/SP, s = idx%SP;
    sF[n][s]    = rhoF[((size_t)n*BATCH + b)*SP + s];
    sF[n][60+s] = rhoB[((size_t)n*BATCH + b)*SP + s];
  }
  for (int idx=tid; idx<120; idx+=256)
    sAB[idx] = (idx<60) ? alphaF[(size_t)b*SP + idx] : alphaB[(size_t)b*SP + idx-60];
  for (int idx=tid; idx<NR*120; idx+=256) sWu[idx] = ldw(Wu_, idx, isbf);
  for (int idx=tid; idx<NN; idx+=256) sHasR[idx] = ldw(hasp_, (size_t)b*NN + idx, isbf);
  __syncthreads();

  for (int idx=tid; idx<NR*NN; idx+=256){
    int r = idx/NN, n = idx%NN;
    const float2* fn = (const float2*)&sF[n][0];
    const float2* wr = (const float2*)&sWu[r*120];
    float acc = ldw(bu_, r, isbf);
    #pragma unroll 6
    for (int s2=0;s2<60;s2++){
      float2 a = fn[s2], c = wr[s2];
      acc += a.x*c.x;
      acc += a.y*c.y;
    }
    sPsi[r][n] = (sHasR[n] != 0.f) ? acc : -60.f;
  }
  if (tid >= 64 && tid < 64+NA){
    int a = tid - 64;
    float acc = ldw(ba_, a, isbf);
    for (int s=0;s<120;s++) acc += sAB[s]*ldw(Wa_, a*120+s, isbf);
    sOm[a] = acc;
  }
  if (tid == 70){
    float acc = ldw(bc_, 0, isbf);
    for (int s=0;s<120;s++) acc += sAB[s]*ldw(Wc_, s, isbf);
    wout(2560 + BATCH*NR*NN + b, acc);                 // value
  }
  __syncthreads();

  if (tid < NR*32){
    const int r = tid >> 5, l = tid & 31;
    float v0 = sPsi[r][l], v1 = sPsi[r][l+32];
    float m = fmaxf(v0, v1);
    #pragma unroll
    for (int o=16;o>0;o>>=1) m = fmaxf(m, __shfl_xor(m, o, 64));
    float e0 = __expf(v0 - m), e1 = __expf(v1 - m);
    float ssum = e0 + e1;
    #pragma unroll
    for (int o=16;o>0;o>>=1) ssum += __shfl_xor(ssum, o, 64);
    float rinv = 1.f/ssum;
    wout(2560 + (size_t)b*NR*NN + r*NN + l,    e0*rinv);   // role_prob
    wout(2560 + (size_t)b*NR*NN + r*NN + l+32, e1*rinv);
  }
  if (tid == 224){   // idle lane in the softmax phase
    float m = -1e30f;
    for (int a=0;a<NA;a++) m = fmaxf(m, sOm[a]);
    float e[NA]; float ssum = 0.f;
    for (int a=0;a<NA;a++){ e[a] = __expf(sOm[a]-m); ssum += e[a]; }
    for (int a=0;a<NA;a++) wout(b*NA + a, e[a]/ssum);  // instr_prob
  }
}

extern "C" void kernel_launch(void* const* d_in, const int* in_sizes, int n_in,
                              void* d_out, int out_size, void* d_ws, size_t ws_size,
                              hipStream_t stream)
{
  const int* adj = (const int*)d_in[3];
  float* ws = (float*)d_ws;

  dir_kernel<<<512, 256, 0, stream>>>(
      adj, d_in[0], d_in[1], d_in[2],
      d_in[4], d_in[5], d_in[6], d_in[7],
      d_in[8], d_in[9], d_in[10], d_in[11],
      d_in[12], d_in[13], d_in[14], d_in[15], ws);

  head_kernel<<<512, 256, 0, stream>>>(
      d_in[2], d_in[16], d_in[17], d_in[18], d_in[19],
      d_in[20], d_in[21], ws, d_out);
}